// Round 3
// baseline (662.549 us; speedup 1.0000x reference)
//
#include <hip/hip_runtime.h>
#include <hip/hip_bf16.h>

typedef __attribute__((ext_vector_type(8))) short short8;
typedef __attribute__((ext_vector_type(4))) float floatx4;

#define D_DIM 256
#define K_DIM 768
#define BM 64      // M rows per block
#define BK 32      // k-slice per step
#define PAD 40     // A LDS row stride in shorts (80B): conflict-free for our access pattern
#define NSTEP 24   // K_DIM / BK
#define BTILE 8192 // shorts per B k-tile (256 cols x 32 k = 16 KB)

// fp32 -> bf16 round-to-nearest-even (no NaN path needed: Gaussian inputs)
__device__ __forceinline__ short f2bf(float x) {
    union { float f; unsigned u; } a; a.f = x;
    unsigned r = a.u + 0x7fffu + ((a.u >> 16) & 1u);
    return (short)(r >> 16);
}

// XOR-swizzle involution within each 1KB window: byte bits[6:4] ^= bits[9:7].
// Chosen so the B fragment ds_read_b128 pattern (col*64 + (lane>>4)*16) is
// bank-conflict-free: per 8-lane cycle, the 8 lanes hit 8 distinct bank groups.
__device__ __forceinline__ unsigned swz(unsigned r) {
    return r ^ (((r >> 7) & 7u) << 4);
}

// W [K_DIM][D_DIM] fp32 -> Wt2: 24 contiguous 16KB k-tiles, tile t holding
// (col 0..255) x (kk 0..31) bf16 at PRE-SWIZZLED byte offsets, so that a linear
// global_load_lds copy + swizzled ds_read reproduce the logical layout (rule:
// swizzle both-sides-or-neither; source permutation == read permutation).
__global__ __launch_bounds__(256) void wt_kernel(const float* __restrict__ W,
                                                 short* __restrict__ Wt2) {
    const int k = blockIdx.x;      // 0..767
    const int n = threadIdx.x;     // 0..255 (output col)
    const int t = k >> 5, kk = k & 31;
    const unsigned r = (unsigned)n * 64u + (unsigned)kk * 2u;  // logical byte offset in tile
    Wt2[(size_t)t * BTILE + (swz(r) >> 1)] = f2bf(W[(size_t)k * D_DIM + n]);
}

// Fused gather + GEMM + bias + relu.
// C tile 64x256 per block (full D in N -> A panel read ONCE).
// 4 waves side by side in N, each wave 64x64 via 4x4 mfma_f32_16x16x32_bf16.
// B staged via global_load_lds (16B width) from the k-tiled pre-swizzled Wt2.
// Counted-vmcnt pipeline (T4): raw s_barrier + lgkmcnt(0); per step exactly
// 6 vmem ops are issued (4 B-DMA + 2 A-loads), so s_waitcnt vmcnt(6) before
// the LDS reads retires exactly all PRIOR steps' ops (vmcnt retires in issue
// order) while this step's B(t+1)/A(t+2) stay in flight ACROSS the barrier.
__global__ __launch_bounds__(256, 3) void edge_gemm(
    const float* __restrict__ edge, const float* __restrict__ node,
    const int* __restrict__ src, const int* __restrict__ tgt,
    const short* __restrict__ Wt2, const float* __restrict__ bias,
    float* __restrict__ out, int E)
{
    __shared__ __align__(16) short As[2][BM][PAD];   // 10240 B
    __shared__ __align__(16) short Bs[2][BTILE];     // 32768 B (total 43 KB -> 3 blocks/CU)

    const int tid = threadIdx.x;
    const int m0 = blockIdx.x * BM;

    // ---- A staging coords: 4 threads per A row, 8 floats each ----
    const int arow = tid >> 2;           // 0..63
    const int achk = (tid & 3) * 8;      // float offset within 32-wide k-slice
    int rs = m0 + arow; if (rs >= E) rs = E - 1;   // clamp tail (stores guarded)
    const int si = src[rs], ti = tgt[rs];
    const float* a0 = edge + (size_t)rs * D_DIM + achk;
    const float* a1 = node + (size_t)si * D_DIM + achk;
    const float* a2 = node + (size_t)ti * D_DIM + achk;

    // ---- MFMA fragment coords ----
    const int lane = tid & 63;
    const int wv = tid >> 6;             // wave 0..3 -> N offset wv*64
    const int fr = lane & 15;            // A row / B col / C col index
    const int kq = (lane >> 4) * 8;      // k-quad offset (shorts)

    // ---- B DMA coords: wave wv stages bytes [wv*4096, wv*4096+4096) per tile ----
    const char* gb = (const char*)Wt2 + wv * 4096 + lane * 16;   // per-lane global src
    char* lb0 = (char*)&Bs[0][0] + wv * 4096;                    // wave-uniform LDS dst
    char* lb1 = (char*)&Bs[1][0] + wv * 4096;

    // ---- swizzled per-thread B read offsets (constant across k-steps) ----
    unsigned boff[4];
#pragma unroll
    for (int j = 0; j < 4; ++j) {
        unsigned col = (unsigned)(wv * 64 + j * 16 + fr);
        boff[j] = swz(col * 64u + (unsigned)(lane >> 4) * 16u);
    }

    floatx4 acc[4][4] = {};
    float4 pA0, pA1, qA0, qA1;           // A ping-pong (2-deep prefetch)

#define GLOADB(t, lb) { \
    const char* g_ = gb + (size_t)(t) * 16384; \
    __builtin_amdgcn_global_load_lds((const __attribute__((address_space(1))) unsigned*)(g_), \
        (__attribute__((address_space(3))) unsigned*)(lb), 16, 0, 0); \
    __builtin_amdgcn_global_load_lds((const __attribute__((address_space(1))) unsigned*)(g_ + 1024), \
        (__attribute__((address_space(3))) unsigned*)((lb) + 1024), 16, 0, 0); \
    __builtin_amdgcn_global_load_lds((const __attribute__((address_space(1))) unsigned*)(g_ + 2048), \
        (__attribute__((address_space(3))) unsigned*)((lb) + 2048), 16, 0, 0); \
    __builtin_amdgcn_global_load_lds((const __attribute__((address_space(1))) unsigned*)(g_ + 3072), \
        (__attribute__((address_space(3))) unsigned*)((lb) + 3072), 16, 0, 0); }

#define LOADA(d0, d1, t) { \
    const int sg_ = (t) >> 3; \
    const float* ab_ = sg_ == 0 ? a0 : (sg_ == 1 ? a1 : a2); \
    const float4* ap_ = (const float4*)(ab_ + ((t) & 7) * BK); \
    d0 = ap_[0]; d1 = ap_[1]; }

#define STOREA(b, s0, s1) { \
    union { short8 v; short s[8]; } u_; \
    u_.s[0] = f2bf(s0.x); u_.s[1] = f2bf(s0.y); u_.s[2] = f2bf(s0.z); u_.s[3] = f2bf(s0.w); \
    u_.s[4] = f2bf(s1.x); u_.s[5] = f2bf(s1.y); u_.s[6] = f2bf(s1.z); u_.s[7] = f2bf(s1.w); \
    *(short8*)&As[b][arow][achk] = u_.v; }

#define COMPUTE(b) { \
    const char* bb_ = (const char*)&Bs[b][0]; \
    short8 bfr0 = *(const short8*)(bb_ + boff[0]); \
    short8 bfr1 = *(const short8*)(bb_ + boff[1]); \
    short8 bfr2 = *(const short8*)(bb_ + boff[2]); \
    short8 bfr3 = *(const short8*)(bb_ + boff[3]); \
    _Pragma("unroll") \
    for (int i_ = 0; i_ < 4; ++i_) { \
        short8 afr = *(const short8*)&As[b][i_ * 16 + fr][kq]; \
        acc[i_][0] = __builtin_amdgcn_mfma_f32_16x16x32_bf16(afr, bfr0, acc[i_][0], 0, 0, 0); \
        acc[i_][1] = __builtin_amdgcn_mfma_f32_16x16x32_bf16(afr, bfr1, acc[i_][1], 0, 0, 0); \
        acc[i_][2] = __builtin_amdgcn_mfma_f32_16x16x32_bf16(afr, bfr2, acc[i_][2], 0, 0, 0); \
        acc[i_][3] = __builtin_amdgcn_mfma_f32_16x16x32_bf16(afr, bfr3, acc[i_][3], 0, 0, 0); \
    } }

// Counted wait: after issuing this step's 6 vmem ops, <=6 outstanding means all
// prior steps' ops retired (in-order retirement). "memory" clobber + sched_barrier
// pin the subsequent LDS reads below the wait.
#define WAIT_PREV { asm volatile("s_waitcnt vmcnt(6)" ::: "memory"); \
                    __builtin_amdgcn_sched_barrier(0); }
#define BAR { asm volatile("s_waitcnt lgkmcnt(0)" ::: "memory"); \
              __builtin_amdgcn_s_barrier(); }

    // ---- prologue: A(0) first so STOREA's auto-wait is vmcnt(4) (B(0) stays in flight) ----
    LOADA(qA0, qA1, 0);          // ops 1-2
    GLOADB(0, lb0);              // ops 3-6
    STOREA(0, qA0, qA1);         // compiler waits its own count for qA regs
    LOADA(qA0, qA1, 1);          // A(1) in flight
    BAR;                         // outstanding: {B(0):4, A(1):2} = 6 (steady-state invariant)

    // ---- main loop: 2 k-steps per iteration, 1 barrier per k-step ----
#pragma unroll 1
    for (int t = 0; t < 22; t += 2) {
        // even: compute step t (buf0); DMA B(t+1)->buf1; write A(t+1); prefetch A(t+2)
        GLOADB(t + 1, lb1);
        LOADA(pA0, pA1, t + 2);
        WAIT_PREV;               // B(t) landed, A(t+1) regs valid
        COMPUTE(0);
        STOREA(1, qA0, qA1);
        BAR;
        // odd: compute step t+1 (buf1); DMA B(t+2)->buf0; write A(t+2); prefetch A(t+3)
        GLOADB(t + 2, lb0);
        LOADA(qA0, qA1, t + 3);
        WAIT_PREV;               // B(t+1) landed, A(t+2) regs valid
        COMPUTE(1);
        STOREA(0, pA0, pA1);
        BAR;
    }
    // step 22: compute buf0; DMA+write step 23 (qA holds A(23))
    GLOADB(23, lb1);
    WAIT_PREV;                   // retires B(22); A(23) waited by compiler at STOREA
    COMPUTE(0);
    STOREA(1, qA0, qA1);
    BAR;
    // step 23: final compute
    asm volatile("s_waitcnt vmcnt(0)" ::: "memory");
    __builtin_amdgcn_sched_barrier(0);
    COMPUTE(1);

#undef GLOADB
#undef LOADA
#undef STOREA
#undef COMPUTE
#undef WAIT_PREV
#undef BAR

    // ---- epilogue: bias + relu + guarded store ----
    float bv[4];
#pragma unroll
    for (int j = 0; j < 4; ++j) bv[j] = bias[wv * 64 + j * 16 + fr];
    const int rq = (lane >> 4) * 4;
#pragma unroll
    for (int i = 0; i < 4; ++i) {
        const int rbase = m0 + i * 16 + rq;
#pragma unroll
        for (int j = 0; j < 4; ++j) {
            const int c = wv * 64 + j * 16 + fr;
#pragma unroll
            for (int r = 0; r < 4; ++r) {
                const int rr = rbase + r;
                if (rr < E) {
                    float v = acc[i][j][r] + bv[j];
                    out[(size_t)rr * D_DIM + c] = v > 0.f ? v : 0.f;
                }
            }
        }
    }
}

extern "C" void kernel_launch(void* const* d_in, const int* in_sizes, int n_in,
                              void* d_out, int out_size, void* d_ws, size_t ws_size,
                              hipStream_t stream) {
    const float* edge = (const float*)d_in[0];
    const float* node = (const float*)d_in[1];
    const int*   srcI = (const int*)d_in[2];
    const int*   tgtI = (const int*)d_in[3];
    const float* W    = (const float*)d_in[4];
    const float* bias = (const float*)d_in[5];
    float* out = (float*)d_out;
    const int E = in_sizes[2];  // n_edges
    short* Wt2 = (short*)d_ws;  // needs NSTEP*BTILE*2 = 393216 bytes

    wt_kernel<<<dim3(K_DIM), dim3(256), 0, stream>>>(W, Wt2);

    dim3 ggrid((E + BM - 1) / BM);   // one block per 64 edge rows, full D in N
    edge_gemm<<<ggrid, dim3(256), 0, stream>>>(edge, node, srcI, tgtI, Wt2, bias, out, E);
}

// Round 4
// 655.794 us; speedup vs baseline: 1.0103x; 1.0103x over previous
//
#include <hip/hip_runtime.h>
#include <hip/hip_bf16.h>

typedef __attribute__((ext_vector_type(8))) short short8;
typedef __attribute__((ext_vector_type(4))) float floatx4;

#define AS1G __attribute__((address_space(1)))
#define AS3L __attribute__((address_space(3)))

#define D_DIM 256
#define K_DIM 768
#define BM 128       // M rows per block
#define NSTEP 24     // K_DIM / 32
#define N_NODES_C 50000

// fp32 -> bf16 round-to-nearest-even
__device__ __forceinline__ short f2bf(float x) {
    union { float f; unsigned u; } a; a.f = x;
    unsigned r = a.u + 0x7fffu + ((a.u >> 16) & 1u);
    return (short)(r >> 16);
}

// B swizzle (unchanged from verified R2/R3): flips byte bits 4-6 by bits 7-9
__device__ __forceinline__ unsigned swzB(unsigned r) { return r ^ (((r >> 7) & 7u) << 4); }
// A swizzle: flips byte bits 4-5 (16B chunk) by row bits 1-2; max 2-way bank alias on reads
__device__ __forceinline__ unsigned swzA(unsigned r) { return r ^ (((r >> 7) & 3u) << 4); }

// W [K][D] fp32 -> Wt2: 24 x 16KB k-tiles, pre-swizzled (swzB) bf16
__global__ __launch_bounds__(256) void wt_kernel(const float* __restrict__ W,
                                                 short* __restrict__ Wt2) {
    const int k = blockIdx.x;      // 0..767
    const int n = threadIdx.x;     // 0..255
    const int t = k >> 5, kk = k & 31;
    const unsigned r = (unsigned)n * 64u + (unsigned)kk * 2u;
    Wt2[(size_t)t * 8192 + (swzB(r) >> 1)] = f2bf(W[(size_t)k * D_DIM + n]);
}

// node fp32 -> bf16, row-major (50000 x 256); grid 6250 x 256 threads, 8 elems/thread exact
__global__ __launch_bounds__(256) void node_cvt(const float* __restrict__ node,
                                                short* __restrict__ nbf) {
    const int i = blockIdx.x * 256 + threadIdx.x;   // short8 group index
    const float4* p = (const float4*)node + (size_t)i * 2;
    float4 f0 = p[0], f1 = p[1];
    union { short8 v; short s[8]; } u;
    u.s[0] = f2bf(f0.x); u.s[1] = f2bf(f0.y); u.s[2] = f2bf(f0.z); u.s[3] = f2bf(f0.w);
    u.s[4] = f2bf(f1.x); u.s[5] = f2bf(f1.y); u.s[6] = f2bf(f1.z); u.s[7] = f2bf(f1.w);
    *((short8*)nbf + i) = u.v;
}

// Fused gather + GEMM + bias + relu. C tile 128x256, 8 waves (2M x 4N), each 64x64.
// NBF=1: node segs staged via 1 global_load_lds per wave per step from bf16 node (prepass).
// NBF=0: fallback, all segs reg-staged fp32->bf16 (if workspace too small).
// Schedule: 1 barrier/step double-buffer; waits (own DMA vmcnt + lgkm) BEFORE the
// barrier so cross-wave staged regions are complete for everyone after it.
template<int NBF>
__global__ __launch_bounds__(512, 4) void edge_gemm(
    const float* __restrict__ edge, const float* __restrict__ node,
    const int* __restrict__ src, const int* __restrict__ tgt,
    const short* __restrict__ Wt2, const short* __restrict__ nodebf,
    const float* __restrict__ bias, float* __restrict__ out, int E)
{
    __shared__ __align__(16) short As[2][4096];   // 2 x 8 KB  (128 rows x 32 k)
    __shared__ __align__(16) short Bs[2][8192];   // 2 x 16 KB (256 cols x 32 k)

    const int tid = threadIdx.x;
    const int m0 = blockIdx.x * BM;

    const int lane = tid & 63, wv = tid >> 6;          // 8 waves
    const int fr = lane & 15, u16 = (lane >> 4) * 16;  // fragment coords
    const int wm = (wv >> 2) * 64, wn = (wv & 3) * 64; // 2M x 4N wave grid

    // ---- staging coords: 4 threads per A row; q chunk XOR-permuted (swzA inverse) ----
    const int srow = tid >> 2;                          // 0..127
    const int q = (tid & 3) ^ ((srow >> 1) & 3);        // logical 16B chunk within 64B k-window
    const int qb = q * 16;
    int rs = m0 + srow; if (rs >= E) rs = E - 1;        // clamp tail (stores guarded)
    const int si = src[rs], ti = tgt[rs];
    const char* eaf = (const char*)edge + (size_t)rs * 1024 + qb * 2;  // fp32 edge row
    const char* nb1; const char* nb2;
    if constexpr (NBF) {
        nb1 = (const char*)nodebf + (size_t)si * 512 + qb;   // bf16 node rows
        nb2 = (const char*)nodebf + (size_t)ti * 512 + qb;
    } else {
        nb1 = (const char*)node + (size_t)si * 1024 + qb * 2; // fp32 node rows
        nb2 = (const char*)node + (size_t)ti * 1024 + qb * 2;
    }

    // ---- B DMA: wave wv stages bytes [wv*2048, +2048) of each 16KB tile (2 instrs) ----
    const char* gbB = (const char*)Wt2 + wv * 2048 + lane * 16;
    char* lbA0 = (char*)As + wv * 1024;
    char* lbA1 = (char*)As + 8192 + wv * 1024;
    char* lbB0 = (char*)Bs + wv * 2048;
    char* lbB1 = (char*)Bs + 16384 + wv * 2048;

    // ---- swizzled read offsets (constant across steps) ----
    unsigned aoff[4], boff[4];
#pragma unroll
    for (int i = 0; i < 4; ++i) { unsigned x = (unsigned)(wm + i * 16 + fr) * 64u + u16; aoff[i] = swzA(x); }
#pragma unroll
    for (int j = 0; j < 4; ++j) { unsigned x = (unsigned)(wn + j * 16 + fr) * 64u + u16; boff[j] = swzB(x); }

    floatx4 acc[4][4] = {};
    float4 pA0, pA1, qA0, qA1;    // edge-phase reg ping-pong

#define GLOADB(t, lb) { \
    const char* g_ = gbB + (size_t)(t) * 16384; \
    __builtin_amdgcn_global_load_lds((const AS1G unsigned*)(g_), (AS3L unsigned*)(lb), 16, 0, 0); \
    __builtin_amdgcn_global_load_lds((const AS1G unsigned*)(g_ + 1024), (AS3L unsigned*)((lb) + 1024), 16, 0, 0); }

#define GLOADA(ts, sp, lb) { \
    __builtin_amdgcn_global_load_lds((const AS1G unsigned*)((sp) + (ts) * 64), (AS3L unsigned*)(lb), 16, 0, 0); }

#define LOADA_S(d0, d1, t) { \
    const char* b_ = (t) < 8 ? eaf : (((t) < 16) ? nb1 : nb2); \
    b_ += ((t) & 7) * 128; \
    d0 = *(const float4*)b_; d1 = *(const float4*)(b_ + 16); }

#define STOREA(bi, s0, s1) { \
    union { short8 v; short s[8]; } u_; \
    u_.s[0] = f2bf(s0.x); u_.s[1] = f2bf(s0.y); u_.s[2] = f2bf(s0.z); u_.s[3] = f2bf(s0.w); \
    u_.s[4] = f2bf(s1.x); u_.s[5] = f2bf(s1.y); u_.s[6] = f2bf(s1.z); u_.s[7] = f2bf(s1.w); \
    *(short8*)((char*)As + (bi) * 8192 + tid * 16) = u_.v; }

#define COMPUTE(bi) { \
    const char* ab_ = (const char*)As + (bi) * 8192; \
    const char* bb_ = (const char*)Bs + (bi) * 16384; \
    short8 bfr0 = *(const short8*)(bb_ + boff[0]); \
    short8 bfr1 = *(const short8*)(bb_ + boff[1]); \
    short8 bfr2 = *(const short8*)(bb_ + boff[2]); \
    short8 bfr3 = *(const short8*)(bb_ + boff[3]); \
    _Pragma("unroll") \
    for (int i_ = 0; i_ < 4; ++i_) { \
        short8 afr = *(const short8*)(ab_ + aoff[i_]); \
        acc[i_][0] = __builtin_amdgcn_mfma_f32_16x16x32_bf16(afr, bfr0, acc[i_][0], 0, 0, 0); \
        acc[i_][1] = __builtin_amdgcn_mfma_f32_16x16x32_bf16(afr, bfr1, acc[i_][1], 0, 0, 0); \
        acc[i_][2] = __builtin_amdgcn_mfma_f32_16x16x32_bf16(afr, bfr2, acc[i_][2], 0, 0, 0); \
        acc[i_][3] = __builtin_amdgcn_mfma_f32_16x16x32_bf16(afr, bfr3, acc[i_][3], 0, 0, 0); \
    } }

// waits BEFORE the barrier: own DMA/ds_write complete -> after barrier, all waves' are.
#define WAIT2 { asm volatile("s_waitcnt vmcnt(2) lgkmcnt(0)" ::: "memory"); __builtin_amdgcn_sched_barrier(0); }
#define WAIT0 { asm volatile("s_waitcnt vmcnt(0) lgkmcnt(0)" ::: "memory"); __builtin_amdgcn_sched_barrier(0); }
#define BARX  { __builtin_amdgcn_s_barrier(); __builtin_amdgcn_sched_barrier(0); }

    // ---- prologue: regs A(0) first (so STOREA's implicit wait leaves B(0) in flight) ----
    LOADA_S(qA0, qA1, 0);        // 2 vmem
    GLOADB(0, lbB0);             // 2 vmem
    STOREA(0, qA0, qA1);         // compiler waits A(0) only
    LOADA_S(qA0, qA1, 1);        // A(1) regs in flight

    if constexpr (NBF) {
        // steps 0..5 (edge, reg-staged, pairs)
#pragma unroll 1
        for (int t = 0; t < 6; t += 2) {
            WAIT2; BARX; GLOADB(t + 1, lbB1); LOADA_S(pA0, pA1, t + 2); COMPUTE(0); STOREA(1, qA0, qA1);
            WAIT2; BARX; GLOADB(t + 2, lbB0); LOADA_S(qA0, qA1, t + 3); COMPUTE(1); STOREA(0, pA0, pA1);
        }
        // t=6: last edge compute with STOREA of A(7)
        WAIT2; BARX; GLOADB(7, lbB1); COMPUTE(0); STOREA(1, qA0, qA1);
        // t=7: first node-DMA stage (A(8) -> As[0])
        WAIT0; BARX; GLOADB(8, lbB0); GLOADA(0, nb1, lbA0); COMPUTE(1);
        // t=8..21 (node, DMA-staged, pairs)
#pragma unroll 1
        for (int t = 8; t < 22; t += 2) {
            const char* s1 = ((t + 1) < 16) ? nb1 : nb2;
            WAIT0; BARX; GLOADB(t + 1, lbB1); GLOADA((t + 1) & 7, s1, lbA1); COMPUTE(0);
            const char* s2 = ((t + 2) < 16) ? nb1 : nb2;
            WAIT0; BARX; GLOADB(t + 2, lbB0); GLOADA((t + 2) & 7, s2, lbA0); COMPUTE(1);
        }
        // t=22: stage A(23)
        WAIT0; BARX; GLOADB(23, lbB1); GLOADA(7, nb2, lbA1); COMPUTE(0);
        // t=23
        WAIT0; BARX; COMPUTE(1);
    } else {
        // fallback: all 24 steps reg-staged (edge + fp32 node gathers)
#pragma unroll 1
        for (int t = 0; t < 22; t += 2) {
            WAIT2; BARX; GLOADB(t + 1, lbB1); LOADA_S(pA0, pA1, t + 2); COMPUTE(0); STOREA(1, qA0, qA1);
            WAIT2; BARX; GLOADB(t + 2, lbB0); LOADA_S(qA0, qA1, t + 3); COMPUTE(1); STOREA(0, pA0, pA1);
        }
        WAIT2; BARX; GLOADB(23, lbB1); COMPUTE(0); STOREA(1, qA0, qA1);
        WAIT0; BARX; COMPUTE(1);
    }

#undef GLOADB
#undef GLOADA
#undef LOADA_S
#undef STOREA
#undef COMPUTE
#undef WAIT2
#undef WAIT0
#undef BARX

    // ---- epilogue: bias + relu + guarded store ----
    float bv[4];
#pragma unroll
    for (int j = 0; j < 4; ++j) bv[j] = bias[wn + j * 16 + fr];
    const int rq = (lane >> 4) * 4;
#pragma unroll
    for (int i = 0; i < 4; ++i) {
        const int rbase = m0 + wm + i * 16 + rq;
#pragma unroll
        for (int j = 0; j < 4; ++j) {
            const int c = wn + j * 16 + fr;
#pragma unroll
            for (int r = 0; r < 4; ++r) {
                const int rr = rbase + r;
                if (rr < E) {
                    float v = acc[i][j][r] + bv[j];
                    out[(size_t)rr * D_DIM + c] = v > 0.f ? v : 0.f;
                }
            }
        }
    }
}

extern "C" void kernel_launch(void* const* d_in, const int* in_sizes, int n_in,
                              void* d_out, int out_size, void* d_ws, size_t ws_size,
                              hipStream_t stream) {
    const float* edge = (const float*)d_in[0];
    const float* node = (const float*)d_in[1];
    const int*   srcI = (const int*)d_in[2];
    const int*   tgtI = (const int*)d_in[3];
    const float* W    = (const float*)d_in[4];
    const float* bias = (const float*)d_in[5];
    float* out = (float*)d_out;
    const int E = in_sizes[2];                       // n_edges

    short* Wt2 = (short*)d_ws;                       // 393216 B
    short* nodebf = (short*)((char*)d_ws + 393216);  // 25.6 MB (N_NODES_C * 256 * 2)
    const size_t WS_NEED = 393216u + (size_t)N_NODES_C * D_DIM * 2u;

    wt_kernel<<<dim3(K_DIM), dim3(256), 0, stream>>>(W, Wt2);

    dim3 ggrid((E + BM - 1) / BM);
    if (ws_size >= WS_NEED) {
        node_cvt<<<dim3(N_NODES_C * D_DIM / 8 / 256), dim3(256), 0, stream>>>(node, nodebf);
        edge_gemm<1><<<ggrid, dim3(512), 0, stream>>>(edge, node, srcI, tgtI, Wt2, nodebf, bias, out, E);
    } else {
        edge_gemm<0><<<ggrid, dim3(512), 0, stream>>>(edge, node, srcI, tgtI, Wt2, nodebf, bias, out, E);
    }
}